// Round 4
// baseline (466.614 us; speedup 1.0000x reference)
//
#include <hip/hip_runtime.h>
#include <hip/hip_bf16.h>

// Bilinear sparse interpolation, two-pass with bf16 intermediate:
//  1) transpose x [B,C,Hx,Wx] fp32 -> xT [B,Hx,Wx,C] bf16 in d_ws
//     (157 MB -- fits in the 256 MB Infinity Cache). x reads are
//     non-temporal so the streamed fp32 input does not evict xT from L3.
//  2) gather: 8 channels per thread (uint4 = 16B per corner load),
//     8 lanes per point, 2 points per thread (8 loads in flight).
//
// R1 evidence: NCHW gather = 7x HBM over-fetch (2.12 GB).
// R2 evidence: fp32 transpose+gather = ~245us on its own roofline.
// R3 (523us): gather 2B-load latency-bound -> vectorized 8x. -53.5us.
// R4 (470us): transpose f32x2 nt loads + dword LDS + uint2 stores. -6.5us
//     -> transpose is near its BW floor (~80us), no longer the lever.
// R6: timed region contains a fixed ~193us ws poison fill + ~40 small
//     memsets/iter (harness reset). Controllable kernel time ~200-270us
//     vs ~100us floor; residual slack pinned on gather MLP: only 4
//     independent 16B loads/thread. -> 2 points/thread = 8 loads in
//     flight. Pre-commit: latency-bound => -25..-35us; null => gather is
//     request/BW-bound, next lever = row-pair 256B merge or bucketing.

constexpr int C_ = 64;
constexpr int Hx_ = 240;
constexpr int Wx_ = 320;
constexpr int HW_ = Hx_ * Wx_;

typedef float f32x4 __attribute__((ext_vector_type(4)));
typedef float f32x2 __attribute__((ext_vector_type(2)));

static __device__ __forceinline__ unsigned short f2bf_raw(float v) {
  __hip_bfloat16 h = __float2bfloat16(v);
  return *reinterpret_cast<unsigned short*>(&h);
}

// bf16 raw (packed pair in a uint) -> float
static __device__ __forceinline__ float bf_lo(unsigned int w) {
  return __uint_as_float(w << 16);
}
static __device__ __forceinline__ float bf_hi(unsigned int w) {
  return __uint_as_float(w & 0xffff0000u);
}

// ---- pass 1: NCHW fp32 -> NHWC bf16 transpose -----------------------------
// block = 256 threads, tile = 128 hw x 64 c.
// LDS layout: tl[c][hw_pair] as dwords (lo16 = even hw, hi16 = odd hw),
// row stride 65 dwords -> both phases hit each bank with exactly 2 lanes
// (free, m136).
// load : f32x2 per thread, wave = 512B contiguous nt reads
// store: repack 4 c-rows into 2 out-dwords via 16-bit merges, uint2 per
//        thread -> wave covers 4 x 128B fully-written segments
__global__ __launch_bounds__(256) void transpose_nchw_nhwc_bf16(
    const float* __restrict__ x, unsigned short* __restrict__ xT) {
  __shared__ unsigned int tl[64 * 65];  // 16.3 KB
  const int t = threadIdx.x;
  const int lane = t & 63;   // hw-pair id for load phase
  const int cg = t >> 6;     // 0..3
  const int hw0 = blockIdx.x * 128;
  const int b = blockIdx.y;

  const float* xin = x + (size_t)b * C_ * HW_ + hw0;
#pragma unroll
  for (int i = 0; i < 16; ++i) {
    const int c = i * 4 + cg;
    // non-temporal: x is streamed exactly once; keep L3 for xT
    const f32x2 v = __builtin_nontemporal_load(
        reinterpret_cast<const f32x2*>(xin + (size_t)c * HW_ + lane * 2));
    const unsigned int pk =
        (unsigned int)f2bf_raw(v.x) | ((unsigned int)f2bf_raw(v.y) << 16);
    tl[c * 65 + lane] = pk;
  }
  __syncthreads();

  // out row (one hw) = 64ch x 2B = 32 dwords = 16 uint2.
  // task e: h = hw-pair (0..63), q = uint2 col (0..15) = channels 4q..4q+3
  unsigned int* xoutd =
      (unsigned int*)(xT + (size_t)b * HW_ * C_ + (size_t)hw0 * C_);
#pragma unroll
  for (int j = 0; j < 4; ++j) {
    const int e = j * 256 + t;
    const int h = e >> 4;   // 0..63
    const int q = e & 15;   // 0..15
    const unsigned int A0 = tl[(4 * q + 0) * 65 + h];
    const unsigned int A1 = tl[(4 * q + 1) * 65 + h];
    const unsigned int A2 = tl[(4 * q + 2) * 65 + h];
    const unsigned int A3 = tl[(4 * q + 3) * 65 + h];
    uint2 lo, hi;
    lo.x = (A0 & 0xffffu) | (A1 << 16);          // hw=2h,   ch 4q,4q+1
    lo.y = (A2 & 0xffffu) | (A3 << 16);          // hw=2h,   ch 4q+2,4q+3
    hi.x = (A0 >> 16) | (A1 & 0xffff0000u);      // hw=2h+1, ch 4q,4q+1
    hi.y = (A2 >> 16) | (A3 & 0xffff0000u);      // hw=2h+1, ch 4q+2,4q+3
    *reinterpret_cast<uint2*>(xoutd + (2 * h) * 32 + 2 * q) = lo;
    *reinterpret_cast<uint2*>(xoutd + (2 * h + 1) * 32 + 2 * q) = hi;
  }
}

// ---- pass 2: gather from NHWC bf16, 8 ch/thread, 2 points/thread ----------
// lane layout: c8 = t&7 (channels 8*c8..8*c8+7), lp = t>>3 (0..31)
// points p0 = bid*64+lp, p1 = p0+32. 8 independent uint4 corner loads
// in flight per thread (128B/lane MLP) to cover L3-hit latency.
__global__ __launch_bounds__(256) void gather_nhwc_bf16_v3(
    const unsigned short* __restrict__ xT, const float* __restrict__ pos,
    const int* __restrict__ Hp, const int* __restrict__ Wp,
    float* __restrict__ out, int N) {
  const int t = threadIdx.x;
  const int c8 = t & 7;
  const int lp = t >> 3;
  const int b = blockIdx.y;
  const int p0 = blockIdx.x * 64 + lp;
  const int p1 = p0 + 32;
  const int N1 = N - 1;
  const int p0c = min(p0, N1);
  const int p1c = min(p1, N1);

  const float Wf = (float)Wp[0];
  const float Hf = (float)Hp[0];

  const float2 xy0 =
      *reinterpret_cast<const float2*>(pos + ((size_t)b * N + p0c) * 2);
  const float2 xy1 =
      *reinterpret_cast<const float2*>(pos + ((size_t)b * N + p1c) * 2);

  const float px0 = xy0.x * (float)(Wx_ - 1) / Wf;
  const float py0 = xy0.y * (float)(Hx_ - 1) / Hf;
  const float px1 = xy1.x * (float)(Wx_ - 1) / Wf;
  const float py1 = xy1.y * (float)(Hx_ - 1) / Hf;

  const int x00 = min(max((int)floorf(px0), 0), Wx_ - 1);
  const int y00 = min(max((int)floorf(py0), 0), Hx_ - 1);
  const int x01 = min(x00 + 1, Wx_ - 1);
  const int y01 = min(y00 + 1, Hx_ - 1);
  const int x10 = min(max((int)floorf(px1), 0), Wx_ - 1);
  const int y10 = min(max((int)floorf(py1), 0), Hx_ - 1);
  const int x11 = min(x10 + 1, Wx_ - 1);
  const int y11 = min(y10 + 1, Hx_ - 1);

  const unsigned short* bb = xT + (size_t)b * (size_t)(HW_ * C_);
  const int co = c8 * 8;  // channel offset within the 64-ch pixel record

  // issue all 8 corner loads up front (independent -> stay in flight)
  const uint4 va0 = *reinterpret_cast<const uint4*>(bb + (y00 * Wx_ + x00) * C_ + co);
  const uint4 vb0 = *reinterpret_cast<const uint4*>(bb + (y01 * Wx_ + x00) * C_ + co);
  const uint4 vc0 = *reinterpret_cast<const uint4*>(bb + (y00 * Wx_ + x01) * C_ + co);
  const uint4 vd0 = *reinterpret_cast<const uint4*>(bb + (y01 * Wx_ + x01) * C_ + co);
  const uint4 va1 = *reinterpret_cast<const uint4*>(bb + (y10 * Wx_ + x10) * C_ + co);
  const uint4 vb1 = *reinterpret_cast<const uint4*>(bb + (y11 * Wx_ + x10) * C_ + co);
  const uint4 vc1 = *reinterpret_cast<const uint4*>(bb + (y10 * Wx_ + x11) * C_ + co);
  const uint4 vd1 = *reinterpret_cast<const uint4*>(bb + (y11 * Wx_ + x11) * C_ + co);

  // point 0 weights + combine
  {
    const float x0f = (float)x00, x1f = (float)x01;
    const float y0f = (float)y00, y1f = (float)y01;
    const float wa = (x1f - px0) * (y1f - py0);
    const float wb = (x1f - px0) * (py0 - y0f);
    const float wc = (px0 - x0f) * (y1f - py0);
    const float wd = (px0 - x0f) * (py0 - y0f);

    f32x4 o0, o1;
    o0.x = wa * bf_lo(va0.x) + wb * bf_lo(vb0.x) + wc * bf_lo(vc0.x) + wd * bf_lo(vd0.x);
    o0.y = wa * bf_hi(va0.x) + wb * bf_hi(vb0.x) + wc * bf_hi(vc0.x) + wd * bf_hi(vd0.x);
    o0.z = wa * bf_lo(va0.y) + wb * bf_lo(vb0.y) + wc * bf_lo(vc0.y) + wd * bf_lo(vd0.y);
    o0.w = wa * bf_hi(va0.y) + wb * bf_hi(vb0.y) + wc * bf_hi(vc0.y) + wd * bf_hi(vd0.y);
    o1.x = wa * bf_lo(va0.z) + wb * bf_lo(vb0.z) + wc * bf_lo(vc0.z) + wd * bf_lo(vd0.z);
    o1.y = wa * bf_hi(va0.z) + wb * bf_hi(vb0.z) + wc * bf_hi(vc0.z) + wd * bf_hi(vd0.z);
    o1.z = wa * bf_lo(va0.w) + wb * bf_lo(vb0.w) + wc * bf_lo(vc0.w) + wd * bf_lo(vd0.w);
    o1.w = wa * bf_hi(va0.w) + wb * bf_hi(vb0.w) + wc * bf_hi(vc0.w) + wd * bf_hi(vd0.w);

    if (p0 < N) {
      float* op = out + ((size_t)b * N + p0) * C_ + co;
      __builtin_nontemporal_store(o0, reinterpret_cast<f32x4*>(op));
      __builtin_nontemporal_store(o1, reinterpret_cast<f32x4*>(op) + 1);
    }
  }

  // point 1 weights + combine
  {
    const float x0f = (float)x10, x1f = (float)x11;
    const float y0f = (float)y10, y1f = (float)y11;
    const float wa = (x1f - px1) * (y1f - py1);
    const float wb = (x1f - px1) * (py1 - y0f);
    const float wc = (px1 - x0f) * (y1f - py1);
    const float wd = (px1 - x0f) * (py1 - y0f);

    f32x4 o0, o1;
    o0.x = wa * bf_lo(va1.x) + wb * bf_lo(vb1.x) + wc * bf_lo(vc1.x) + wd * bf_lo(vd1.x);
    o0.y = wa * bf_hi(va1.x) + wb * bf_hi(vb1.x) + wc * bf_hi(vc1.x) + wd * bf_hi(vd1.x);
    o0.z = wa * bf_lo(va1.y) + wb * bf_lo(vb1.y) + wc * bf_lo(vc1.y) + wd * bf_lo(vd1.y);
    o0.w = wa * bf_hi(va1.y) + wb * bf_hi(vb1.y) + wc * bf_hi(vc1.y) + wd * bf_hi(vd1.y);
    o1.x = wa * bf_lo(va1.z) + wb * bf_lo(vb1.z) + wc * bf_lo(vc1.z) + wd * bf_lo(vd1.z);
    o1.y = wa * bf_hi(va1.z) + wb * bf_hi(vb1.z) + wc * bf_hi(vc1.z) + wd * bf_hi(vd1.z);
    o1.z = wa * bf_lo(va1.w) + wb * bf_lo(vb1.w) + wc * bf_lo(vc1.w) + wd * bf_lo(vd1.w);
    o1.w = wa * bf_hi(va1.w) + wb * bf_hi(vb1.w) + wc * bf_hi(vc1.w) + wd * bf_hi(vd1.w);

    if (p1 < N) {
      float* op = out + ((size_t)b * N + p1) * C_ + co;
      __builtin_nontemporal_store(o0, reinterpret_cast<f32x4*>(op));
      __builtin_nontemporal_store(o1, reinterpret_cast<f32x4*>(op) + 1);
    }
  }
}

// ---- fallback (direct NCHW gather) if ws too small ------------------------
#define BQ 4  // points per block

__global__ __launch_bounds__(256) void gather_nchw_direct(
    const float* __restrict__ x, const float* __restrict__ pos,
    const int* __restrict__ Hp, const int* __restrict__ Wp,
    float* __restrict__ out, int N) {
  const int t = threadIdx.x;
  const int c = t & 63;
  const int p = blockIdx.x * BQ + (t >> 6);
  const int b = blockIdx.y;
  if (p >= N) return;

  const float Wf = (float)Wp[0];
  const float Hf = (float)Hp[0];
  const float* pp = pos + ((size_t)b * N + p) * 2;
  const float px = pp[0] * (float)(Wx_ - 1) / Wf;
  const float py = pp[1] * (float)(Hx_ - 1) / Hf;

  int x0 = min(max((int)floorf(px), 0), Wx_ - 1);
  int y0 = min(max((int)floorf(py), 0), Hx_ - 1);
  const int x1 = min(x0 + 1, Wx_ - 1);
  const int y1 = min(y0 + 1, Hx_ - 1);

  const float x0f = (float)x0, x1f = (float)x1;
  const float y0f = (float)y0, y1f = (float)y1;
  const float wa = (x1f - px) * (y1f - py);
  const float wb = (x1f - px) * (py - y0f);
  const float wc = (px - x0f) * (y1f - py);
  const float wd = (px - x0f) * (py - y0f);

  const float* plane = x + (size_t)(b * C_ + c) * HW_;
  const int r0 = y0 * Wx_;
  const int r1 = y1 * Wx_;
  const float Ia = plane[r0 + x0];
  const float Ib = plane[r1 + x0];
  const float Ic = plane[r0 + x1];
  const float Id = plane[r1 + x1];

  out[((size_t)b * N + p) * C_ + c] = wa * Ia + wb * Ib + wc * Ic + wd * Id;
}

extern "C" void kernel_launch(void* const* d_in, const int* in_sizes, int n_in,
                              void* d_out, int out_size, void* d_ws, size_t ws_size,
                              hipStream_t stream) {
  const float* x = (const float*)d_in[0];
  const float* pos = (const float*)d_in[1];
  const int* Hp = (const int*)d_in[2];
  const int* Wp = (const int*)d_in[3];
  float* out = (float*)d_out;

  const int B = 16;
  const int N = in_sizes[1] / (B * 2);

  const size_t need = (size_t)B * C_ * HW_ * sizeof(unsigned short);  // 157 MB
  if (ws_size >= need) {
    unsigned short* xT = (unsigned short*)d_ws;
    dim3 tgrid(HW_ / 128, B);  // 600 x 16
    transpose_nchw_nhwc_bf16<<<tgrid, 256, 0, stream>>>(x, xT);
    dim3 ggrid((N + 63) / 64, B);  // 64 points / block (2 per thread)
    gather_nhwc_bf16_v3<<<ggrid, 256, 0, stream>>>(xT, pos, Hp, Wp, out, N);
  } else {
    dim3 ggrid((N + BQ - 1) / BQ, B);
    gather_nchw_direct<<<ggrid, 256, 0, stream>>>(x, pos, Hp, Wp, out, N);
  }
}